// Round 7
// baseline (49.317 us; speedup 1.0000x reference)
//
#include <hip/hip_runtime.h>

// PixelEffectModule: 8-bin intensity histogram over 11x11 windows at stride 8,
// argmax bin, output that bin's mean RGB, upsampled 8x8.
// Input: rgb (1,3,2048,2048) fp32 in [0,255). Output: (1,3,2048,2048) fp32.
//
// R7 = R6's math path (bin -> packed-u64 count + 8-way predicated FMA -> argmax)
// with TLP/pressure fixes:
//  - wave = 32 cells x 2 row-band parts (lanes 0-31: part 2w, lanes 32-63:
//    part 2w+1, same cells). 8 parts of rows 2/2/2/1/1/1/1/1. Grid 2048 WGs
//    -> 8 WG/CU reachable (R6 was grid-capped at 4).
//  - per-quad processing (12 live px floats, not 48) to stay under 64 VGPR:
//    R6's WRITE_SIZE=103MB (output is 48MB) indicated scratch spill.
//  - cross-half reduce via __shfl_xor(32); only 4-wave reduce uses LDS (13KB).
//  - XCD swizzle: slot=(wgid&7)*256+(wgid>>3) -> each XCD owns 32 cell-rows.

#define Wd 2048
#define HW (2048 * 2048)

typedef unsigned int u32;
typedef unsigned long long u64;

// correctly-rounded t/3 (Markstein), 3 ops vs ~9-inst div expansion
__device__ __forceinline__ float div3(float t) {
    const float c = 0x1.555556p-2f;  // RN(1/3)
    float q0 = t * c;
    float r  = __builtin_fmaf(q0, -3.0f, t);
    return __builtin_fmaf(r, c, q0);
}

__global__ __launch_bounds__(256, 4)
void pixel_effect_kernel(const float* __restrict__ rgb, float* __restrict__ out) {
    const int w    = threadIdx.x >> 6;         // wave 0..3
    const int half = (threadIdx.x >> 5) & 1;   // half-wave
    const int cl   = threadIdx.x & 31;         // cell within 32-strip
    const int p    = 2 * w + half;             // row-band part 0..7

    // XCD swizzle (grid 2048 = 8*256, bijective): XCD (wgid&7) owns slots
    // [256*xcd, 256*xcd+256) = 32 contiguous cell-rows.
    u32 wgid = blockIdx.x;
    u32 slot = (wgid & 7u) * 256u + (wgid >> 3);
    const int oy  = (int)(slot >> 3);
    const int bx8 = (int)(slot & 7u);
    const int ox  = bx8 * 32 + cl;

    const float* Rp = rgb;
    const float* Gp = rgb + HW;
    const float* Bp = rgb + 2 * HW;

    // slot j maps x = xbase + j. Interior: xbase=8*(ox-1), valid j in [3,13].
    // ox==0: xbase=0, valid j in [0,5]. All 4 quads always in bounds.
    const int xbase = (ox == 0) ? 0 : ox * 8 - 8;
    const u32 vmask = (ox == 0) ? 0x003Fu : 0x3FF8u;
    const int ytop  = oy * 8 - 5;
    const int rs = (p < 3) ? 2 * p : (3 + p);  // first window-row of this part
    const int nr = (p < 3) ? 2 : 1;            // rows: 2,2,2,1,1,1,1,1

    u64 c64 = 0;
    float sR[8], sG[8], sB[8];
#pragma unroll
    for (int b = 0; b < 8; ++b) { sR[b] = 0.f; sG[b] = 0.f; sB[b] = 0.f; }

    // ---- single pass, one float4-quad at a time (low register pressure) ----
#pragma unroll
    for (int k = 0; k < 2; ++k) {
        int y = ytop + rs + k;                 // uniform within half-wave
        if (k < nr && y >= 0) {
            int off = y * Wd + xbase;
#pragma unroll
            for (int q = 0; q < 4; ++q) {
                float4 r4 = *(const float4*)(Rp + off + 4 * q);
                float4 g4 = *(const float4*)(Gp + off + 4 * q);
                float4 b4 = *(const float4*)(Bp + off + 4 * q);
                float vr[4] = { r4.x, r4.y, r4.z, r4.w };
                float vg[4] = { g4.x, g4.y, g4.z, g4.w };
                float vb[4] = { b4.x, b4.y, b4.z, b4.w };
#pragma unroll
                for (int jj = 0; jj < 4; ++jj) {
                    int j = 4 * q + jj;
                    if (j >= 14) continue;
                    float m = div3(vr[jj] + vg[jj] + vb[jj]);
                    u32 bin = (u32)(m * 0.03125f);   // trunc(mean/32), exact
                    u32 valid = (vmask >> j) & 1u;
                    c64 += (u64)valid << (bin << 3);
                    u32 binv = valid ? bin : 15u;    // 15 matches no bin
#pragma unroll
                    for (int b = 0; b < 8; ++b) {
                        float hm = (binv == (u32)b) ? 1.0f : 0.0f;
                        sR[b] = __builtin_fmaf(hm, vr[jj], sR[b]);
                        sG[b] = __builtin_fmaf(hm, vg[jj], sG[b]);
                        sB[b] = __builtin_fmaf(hm, vb[jj], sB[b]);
                    }
                }
            }
        }
    }

    // ---- cross-half reduce (parts 2w + 2w+1) in-register ----
    c64 += __shfl_xor(c64, 32);
#pragma unroll
    for (int b = 0; b < 8; ++b) {
        sR[b] += __shfl_xor(sR[b], 32);
        sG[b] += __shfl_xor(sG[b], 32);
        sB[b] += __shfl_xor(sB[b], 32);
    }

    __shared__ u64   sc[4][32];
    __shared__ float ssr[4][8][32];
    __shared__ float ssg[4][8][32];
    __shared__ float ssb[4][8][32];
    if (half == 0) {
        sc[w][cl] = c64;
#pragma unroll
        for (int b = 0; b < 8; ++b) {
            ssr[w][b][cl] = sR[b];
            ssg[w][b][cl] = sG[b];
            ssb[w][b][cl] = sB[b];
        }
    }
    __syncthreads();

    // ---- total counts + argmax (first-max wins, matches jnp.argmax) ----
    u64 tot = sc[0][cl] + sc[1][cl] + sc[2][cl] + sc[3][cl];   // bytes <=121
    u32 lo = (u32)tot, hi = (u32)(tot >> 32);
    u32 best = 0, bc = lo & 0xFFu;
#pragma unroll
    for (int b = 1; b < 8; ++b) {
        u32 cb = ((b < 4 ? lo : hi) >> ((b & 3) * 8)) & 0xFFu;
        bool t = cb > bc;
        bc   = t ? cb : bc;
        best = t ? (u32)b : best;
    }

    // ---- gather winning bin's sums (bank = cl: conflict-free broadcast) ----
    int bi = (int)best;
    float tr = 0.f, tg = 0.f, tb = 0.f;
#pragma unroll
    for (int i = 0; i < 4; ++i) {
        tr += ssr[i][bi][cl];
        tg += ssg[i][bi][cl];
        tb += ssb[i][bi][cl];
    }
    float fbc = (float)bc;
    float orv = tr / fbc, ogv = tg / fbc, obv = tb / fbc;

    // ---- write: part p owns row p of the 8x8 block, 2x float4 per channel ----
    size_t base = (size_t)(oy * 8 + p) * Wd + (size_t)(ox * 8);
    float vals[3] = { orv, ogv, obv };
#pragma unroll
    for (int c = 0; c < 3; ++c) {
        float v = vals[c];
        float4 vv = make_float4(v, v, v, v);
        float* o = out + (size_t)c * HW + base;
        ((float4*)o)[0] = vv;
        ((float4*)o)[1] = vv;
    }
}

extern "C" void kernel_launch(void* const* d_in, const int* in_sizes, int n_in,
                              void* d_out, int out_size, void* d_ws, size_t ws_size,
                              hipStream_t stream) {
    const float* rgb = (const float*)d_in[0];
    float* out = (float*)d_out;
    dim3 block(256, 1, 1);                // 4 waves; wave = 32 cells x 2 parts
    dim3 grid(2048, 1, 1);                // 8 strips/cell-row x 256 rows (swizzled)
    hipLaunchKernelGGL(pixel_effect_kernel, grid, block, 0, stream, rgb, out);
}

// Round 8
// 39.397 us; speedup vs baseline: 1.2518x; 1.2518x over previous
//
#include <hip/hip_runtime.h>

// PixelEffectModule: 8-bin intensity histogram over 11x11 windows at stride 8,
// argmax bin, output that bin's mean RGB, upsampled 8x8.
// Input: rgb (1,3,2048,2048) fp32 in [0,255). Output: (1,3,2048,2048) fp32.
//
// R8 = R6 with ONE delta: amdgpu_waves_per_eu(4,4) instead of
// __launch_bounds__(256,4). R6/R7 showed WRITE_SIZE inflation (103/130 MB vs
// 48 MB output) with VGPR pinned at 64: the allocator targeted 8 waves/EU and
// spilled the ~50-reg live set (24 bin accumulators) to scratch; dirty scratch
// lines evict to HBM (+WRITE), reloads hit L2 (FETCH clean). Pinning
// occupancy to 4 waves/EU (cap+target) gives the allocator 128 VGPRs -> no
// spill. Everything else (math path, LDS layout, swizzle, writes) identical
// to the green R6 baseline (38.2 us).

#define Wd 2048
#define Hd 2048
#define HW (Wd * Hd)

typedef unsigned int u32;
typedef unsigned long long u64;

// correctly-rounded t/3 (Markstein), 3 ops vs ~9-inst div expansion
__device__ __forceinline__ float div3(float t) {
    const float c = 0x1.555556p-2f;  // RN(1/3)
    float q0 = t * c;
    float r  = __builtin_fmaf(q0, -3.0f, t);
    return __builtin_fmaf(r, c, q0);
}

__global__ __attribute__((amdgpu_flat_work_group_size(256, 256), amdgpu_waves_per_eu(4, 4)))
void pixel_effect_kernel(const float* __restrict__ rgb, float* __restrict__ out) {
    const int lx = threadIdx.x;          // cell lane 0..63
    const int p  = threadIdx.y;          // row-band part 0..3 (= wave index)

    // XCD swizzle: grid=1024 (multiple of 8) -> bijective. XCD (wgid&7) gets
    // slots [128*xcd, 128*xcd+128) = 32 contiguous cell-rows.
    u32 wgid = blockIdx.x;
    u32 slot = (wgid & 7u) * 128u + (wgid >> 3);
    const int oy = (int)(slot >> 2);
    const int bx = (int)(slot & 3u);
    const int ox = bx * 64 + lx;

    const float* Rp = rgb;
    const float* Gp = rgb + HW;
    const float* Bp = rgb + 2 * HW;

    // slot j maps x = xbase + j. Interior: xbase=8*(ox-1), valid j in [3,13].
    // ox==0: xbase=0, valid j in [0,5]. Loads (4 quads/ch) always in bounds.
    const int xbase = (ox == 0) ? 0 : ox * 8 - 8;
    const u32 vmask = (ox == 0) ? 0x003Fu : 0x3FF8u;
    const int ytop  = oy * 8 - 5;
    const int rbase = p * 3;             // first window-row of this band
    const int nr    = (p < 3) ? 3 : 2;   // rows per band: 3/3/3/2

    __shared__ u64   sc[4][64];          // packed byte counts per part
    __shared__ float ssr[4][8][64];      // per part, bin, lane: r-sum
    __shared__ float ssg[4][8][64];
    __shared__ float ssb[4][8][64];

    u64 c64 = 0;
    float sR[8], sG[8], sB[8];
#pragma unroll
    for (int b = 0; b < 8; ++b) { sR[b] = 0.f; sG[b] = 0.f; sB[b] = 0.f; }

    // ---- single pass: bin pixels, count + per-bin predicated sums ----
#pragma unroll
    for (int k = 0; k < 3; ++k) {
        int y = ytop + rbase + k;        // wave-uniform; only top edge clips
        if (k < nr && y >= 0) {
            int off = y * Wd + xbase;
            float vR[16], vG[16], vB[16];
#pragma unroll
            for (int q = 0; q < 4; ++q) {
                *(float4*)(vR + 4 * q) = *(const float4*)(Rp + off + 4 * q);
                *(float4*)(vG + 4 * q) = *(const float4*)(Gp + off + 4 * q);
                *(float4*)(vB + 4 * q) = *(const float4*)(Bp + off + 4 * q);
            }
#pragma unroll
            for (int j = 0; j < 14; ++j) {
                float m = div3(vR[j] + vG[j] + vB[j]);
                u32 bin = (u32)(m * 0.03125f);       // trunc(mean/32), exact
                u32 valid = (vmask >> j) & 1u;
                c64 += (u64)valid << (bin << 3);
                u32 binv = valid ? bin : 15u;        // 15 matches no bin
#pragma unroll
                for (int b = 0; b < 8; ++b) {
                    float hm = (binv == (u32)b) ? 1.0f : 0.0f;
                    sR[b] = __builtin_fmaf(hm, vR[j], sR[b]);
                    sG[b] = __builtin_fmaf(hm, vG[j], sG[b]);
                    sB[b] = __builtin_fmaf(hm, vB[j], sB[b]);
                }
            }
        }
    }
    sc[p][lx] = c64;
#pragma unroll
    for (int b = 0; b < 8; ++b) {
        ssr[p][b][lx] = sR[b];
        ssg[p][b][lx] = sG[b];
        ssb[p][b][lx] = sB[b];
    }
    __syncthreads();

    // ---- total counts + argmax (first-max wins, matches jnp.argmax) ----
    u64 tot = sc[0][lx] + sc[1][lx] + sc[2][lx] + sc[3][lx];  // bytes <=121
    u32 lo = (u32)tot, hi = (u32)(tot >> 32);
    u32 best = 0, bc = lo & 0xFFu;
#pragma unroll
    for (int b = 1; b < 8; ++b) {
        u32 cb = ((b < 4 ? lo : hi) >> ((b & 3) * 8)) & 0xFFu;
        bool t = cb > bc;
        bc   = t ? cb : bc;
        best = t ? (u32)b : best;
    }

    // ---- gather winning bin's sums (bank = lx&31 for any best: no conflict) ----
    int bi = (int)best;
    float tr = 0.f, tg = 0.f, tb = 0.f;
#pragma unroll
    for (int i = 0; i < 4; ++i) {
        tr += ssr[i][bi][lx];
        tg += ssg[i][bi][lx];
        tb += ssb[i][bi][lx];
    }
    float fbc = (float)bc;
    float orv = tr / fbc, ogv = tg / fbc, obv = tb / fbc;

    // ---- write: band p owns rows 2p, 2p+1 of the 8x8 block (as R4) ----
    size_t base = (size_t)(oy * 8 + p * 2) * Wd + (size_t)(ox * 8);
    float vals[3] = { orv, ogv, obv };
#pragma unroll
    for (int c = 0; c < 3; ++c) {
        float v = vals[c];
        float4 vv = make_float4(v, v, v, v);
        float* o0 = out + (size_t)c * HW + base;
        ((float4*)o0)[0] = vv;  ((float4*)o0)[1] = vv;
        float* o1 = o0 + Wd;
        ((float4*)o1)[0] = vv;  ((float4*)o1)[1] = vv;
    }
}

extern "C" void kernel_launch(void* const* d_in, const int* in_sizes, int n_in,
                              void* d_out, int out_size, void* d_ws, size_t ws_size,
                              hipStream_t stream) {
    const float* rgb = (const float*)d_in[0];
    float* out = (float*)d_out;
    dim3 block(64, 4, 1);                 // 4 waves; tid.y = row-band = wave idx
    dim3 grid(1024, 1, 1);                // 4 col-groups x 256 cell-rows (swizzled)
    hipLaunchKernelGGL(pixel_effect_kernel, grid, block, 0, stream, rgb, out);
}

// Round 9
// 32.465 us; speedup vs baseline: 1.5191x; 1.2135x over previous
//
#include <hip/hip_runtime.h>

// PixelEffectModule: 8-bin intensity histogram over 11x11 windows at stride 8,
// argmax bin, output that bin's mean RGB, upsampled 8x8.
// Input: rgb (1,3,2048,2048) fp32 in [0,255). Output: (1,3,2048,2048) fp32.
//
// R9 = R7's verified parts=8 skeleton (absmax 0.0: swizzle, half-wave split,
// shfl reduces, argmax, writes) + R4's verified two-pass nibble-cache math
// (WRITE-clean) in place of the 24 per-bin FMA accumulators that correlate
// with WRITE_SIZE inflation (R6/R7/R8 ~2x; R1/R3/R4 exact 48 MB).
//  - wave = 32 cells x 2 row-band parts; parts 0..7 rows 2/2/2/1/1/1/1/1
//  - pass 1: packed-u64 counts + per-px bin nibbles (4 regs)
//  - pass 2: re-read own rows (L1/L2-hot), 3 predicated FMA on winning bin
//  - live set ~40 regs -> no spill at the 64-VGPR/8-wave allocator target
//  - grid 2048 = 8 WG/CU -> 32 waves/CU (100% occupancy ceiling); LDS 3 KB

#define Wd 2048
#define HW (2048 * 2048)

typedef unsigned int u32;
typedef unsigned long long u64;

// correctly-rounded t/3 (Markstein), 3 ops vs ~9-inst div expansion
__device__ __forceinline__ float div3(float t) {
    const float c = 0x1.555556p-2f;  // RN(1/3)
    float q0 = t * c;
    float r  = __builtin_fmaf(q0, -3.0f, t);
    return __builtin_fmaf(r, c, q0);
}

__global__ __launch_bounds__(256, 8)
void pixel_effect_kernel(const float* __restrict__ rgb, float* __restrict__ out) {
    const int w    = threadIdx.x >> 6;         // wave 0..3
    const int half = (threadIdx.x >> 5) & 1;   // half-wave
    const int cl   = threadIdx.x & 31;         // cell within 32-strip
    const int p    = 2 * w + half;             // row-band part 0..7

    // XCD swizzle (grid 2048 = 8*256, bijective): XCD (wgid&7) owns slots
    // [256*xcd, 256*xcd+256) = 32 contiguous cell-rows.
    u32 wgid = blockIdx.x;
    u32 slot = (wgid & 7u) * 256u + (wgid >> 3);
    const int oy  = (int)(slot >> 3);
    const int bx8 = (int)(slot & 7u);
    const int ox  = bx8 * 32 + cl;

    const float* Rp = rgb;
    const float* Gp = rgb + HW;
    const float* Bp = rgb + 2 * HW;

    // slot j maps x = xbase + j. Interior: xbase=8*(ox-1), valid j in [3,13].
    // ox==0: xbase=0, valid j in [0,5]. All 4 quads always in bounds.
    const int xbase = (ox == 0) ? 0 : ox * 8 - 8;
    const u32 vmask = (ox == 0) ? 0x003Fu : 0x3FF8u;
    const int ytop  = oy * 8 - 5;
    const int rs = (p < 3) ? 2 * p : (3 + p);  // first window-row of this part
    const int nr = (p < 3) ? 2 : 1;            // rows: 2,2,2,1,1,1,1,1

    u64 c64 = 0;
    u32 nbl[2], nbh[2];                        // per-row packed bins (4b/px)

    // ---- pass 1: bin pixels, packed byte counts + nibble cache ----
#pragma unroll
    for (int k = 0; k < 2; ++k) {
        nbl[k] = 0xFFFFFFFFu; nbh[k] = 0xFFFFFFFFu;
        int y = ytop + rs + k;                 // uniform per half-wave
        if (k < nr && y >= 0) {
            int off = y * Wd + xbase;
            u32 bl = 0, bh = 0;
#pragma unroll
            for (int q = 0; q < 4; ++q) {
                float4 r4 = *(const float4*)(Rp + off + 4 * q);
                float4 g4 = *(const float4*)(Gp + off + 4 * q);
                float4 b4 = *(const float4*)(Bp + off + 4 * q);
                const float vr[4] = { r4.x, r4.y, r4.z, r4.w };
                const float vg[4] = { g4.x, g4.y, g4.z, g4.w };
                const float vb[4] = { b4.x, b4.y, b4.z, b4.w };
#pragma unroll
                for (int jj = 0; jj < 4; ++jj) {
                    int j = 4 * q + jj;
                    if (j >= 14) continue;
                    float m = div3(vr[jj] + vg[jj] + vb[jj]);
                    u32 bin = (u32)(m * 0.03125f);   // trunc(mean/32), exact
                    u32 valid = (vmask >> j) & 1u;
                    c64 += (u64)valid << (bin << 3);
                    u32 binv = valid ? bin : 15u;    // 15 matches no bin
                    if (j < 8) bl |= binv << (4 * j);
                    else       bh |= binv << (4 * (j - 8));
                }
            }
            nbl[k] = bl; nbh[k] = bh;
        }
    }

    // ---- cross-half reduce (parts 2w, 2w+1), then 4-wave LDS reduce ----
    c64 += __shfl_xor(c64, 32);

    __shared__ u64 sc[4][32];
    if (half == 0) sc[w][cl] = c64;
    __syncthreads();

    u64 tot = sc[0][cl] + sc[1][cl] + sc[2][cl] + sc[3][cl];   // bytes <=121
    u32 lo = (u32)tot, hi = (u32)(tot >> 32);
    u32 best = 0, bc = lo & 0xFFu;
#pragma unroll
    for (int b = 1; b < 8; ++b) {
        u32 cb = ((b < 4 ? lo : hi) >> ((b & 3) * 8)) & 0xFFu;
        bool t = cb > bc;
        bc   = t ? cb : bc;
        best = t ? (u32)b : best;
    }

    // ---- pass 2: re-read own rows (hot), sum winning bin via nibbles ----
    float sr = 0.f, sg = 0.f, sb = 0.f;
#pragma unroll
    for (int k = 0; k < 2; ++k) {
        int y = ytop + rs + k;
        if (k < nr && y >= 0) {
            int off = y * Wd + xbase;
            u32 bl = nbl[k], bh = nbh[k];
#pragma unroll
            for (int q = 0; q < 4; ++q) {
                float4 r4 = *(const float4*)(Rp + off + 4 * q);
                float4 g4 = *(const float4*)(Gp + off + 4 * q);
                float4 b4 = *(const float4*)(Bp + off + 4 * q);
                const float vr[4] = { r4.x, r4.y, r4.z, r4.w };
                const float vg[4] = { g4.x, g4.y, g4.z, g4.w };
                const float vb[4] = { b4.x, b4.y, b4.z, b4.w };
#pragma unroll
                for (int jj = 0; jj < 4; ++jj) {
                    int j = 4 * q + jj;
                    if (j >= 14) continue;
                    u32 bin = ((j < 8) ? (bl >> (4 * j))
                                       : (bh >> (4 * (j - 8)))) & 0xFu;
                    float hm = (bin == best) ? 1.0f : 0.0f;
                    sr = __builtin_fmaf(hm, vr[jj], sr);
                    sg = __builtin_fmaf(hm, vg[jj], sg);
                    sb = __builtin_fmaf(hm, vb[jj], sb);
                }
            }
        }
    }
    sr += __shfl_xor(sr, 32);
    sg += __shfl_xor(sg, 32);
    sb += __shfl_xor(sb, 32);

    __shared__ float4 ss[4][32];
    if (half == 0) ss[w][cl] = make_float4(sr, sg, sb, 0.f);
    __syncthreads();

    float4 s0 = ss[0][cl], s1 = ss[1][cl], s2 = ss[2][cl], s3 = ss[3][cl];
    float fbc = (float)bc;
    float orv = (s0.x + s1.x + s2.x + s3.x) / fbc;
    float ogv = (s0.y + s1.y + s2.y + s3.y) / fbc;
    float obv = (s0.z + s1.z + s2.z + s3.z) / fbc;

    // ---- write: part p owns row p of the 8x8 block, 2x float4 per channel ----
    size_t base = (size_t)(oy * 8 + p) * Wd + (size_t)(ox * 8);
    float vals[3] = { orv, ogv, obv };
#pragma unroll
    for (int c = 0; c < 3; ++c) {
        float v = vals[c];
        float4 vv = make_float4(v, v, v, v);
        float* o = out + (size_t)c * HW + base;
        ((float4*)o)[0] = vv;
        ((float4*)o)[1] = vv;
    }
}

extern "C" void kernel_launch(void* const* d_in, const int* in_sizes, int n_in,
                              void* d_out, int out_size, void* d_ws, size_t ws_size,
                              hipStream_t stream) {
    const float* rgb = (const float*)d_in[0];
    float* out = (float*)d_out;
    dim3 block(256, 1, 1);                // 4 waves; wave = 32 cells x 2 parts
    dim3 grid(2048, 1, 1);                // 8 strips/cell-row x 256 rows (swizzled)
    hipLaunchKernelGGL(pixel_effect_kernel, grid, block, 0, stream, rgb, out);
}